// Round 1
// 278.333 us; speedup vs baseline: 1.0171x; 1.0171x over previous
//
#include <hip/hip_runtime.h>
#include <hip/hip_bf16.h>

using bf16x8 = __attribute__((ext_vector_type(8))) __bf16;
using f32x4  = __attribute__((ext_vector_type(4))) float;

#define NB 8
#define SEQ 1024
#define HEADS 16
#define HD 64
#define EMB 1024

// exp domain: prefer native exp2 (one v_exp_f32), fold log2(e) into the Q prescale.
#if __has_builtin(__builtin_amdgcn_exp2f)
  #define EXPD(x) __builtin_amdgcn_exp2f(x)
  #define QSCALE  0.04508422f    /* (1/32) * log2(e) */
  #define MASKV  -4.5084e18f     /* -1e20 * QSCALE   */
#else
  #define EXPD(x) __expf(x)
  #define QSCALE  0.03125f
  #define MASKV  -3.125e18f
#endif

__device__ __forceinline__ int cvtpk_bf16(float lo, float hi) {
    int r;
    asm("v_cvt_pk_bf16_f32 %0, %1, %2" : "=v"(r) : "v"(lo), "v"(hi));
    return r;
}

__device__ __forceinline__ void gld16(const __bf16* g, __bf16* l) {
    __builtin_amdgcn_global_load_lds((const __attribute__((address_space(1))) void*)g,
                                     (__attribute__((address_space(3))) void*)l, 16, 0, 0);
}

// ---------------- Kernel 0: bit-pack mask (N,SEQ,SEQ) i32 -> (N,SEQ,SEQ/64) u64 ----------------
__global__ __launch_bounds__(256) void mask_pack(const int* __restrict__ mask,
                                                 unsigned long long* __restrict__ mp)
{
    const int row = blockIdx.x, n = blockIdx.y, t = threadIdx.x;
    const int w = t >> 6, lane = t & 63;
    const int* m = mask + ((size_t)n * SEQ + row) * SEQ;
    #pragma unroll
    for (int i = 0; i < 4; ++i) {
        unsigned long long b = __ballot(m[i * 256 + w * 64 + lane] != 0);
        if (lane == 0) mp[((size_t)n * SEQ + row) * 16 + i * 4 + w] = b;
    }
}

// ---------------- Kernel 1: per-head projection, MFMA ----------------
// z=0: Q out (N,H,SEQ,64), pre-scaled by QSCALE.  z=1: K out.  z=2: V out transposed (N,H,64,SEQ).
__global__ __launch_bounds__(256, 4) void proj_mfma(
    const float* __restrict__ q_in, const float* __restrict__ k_in, const float* __restrict__ v_in,
    const float* __restrict__ Wq, const float* __restrict__ Wk, const float* __restrict__ Wv,
    __bf16* __restrict__ qp, __bf16* __restrict__ kp, __bf16* __restrict__ vpt)
{
    const int z = blockIdx.z;
    const float* X  = (z == 0) ? q_in : (z == 1) ? k_in : v_in;
    const float* Wf = (z == 0) ? Wq   : (z == 1) ? Wk   : Wv;

    __shared__ __align__(16) __bf16 Wb[64 * 72];  // Wb[e][d]
    __shared__ __align__(16) __bf16 Xb[64 * 72];  // Xb[l][d]; reused as output tile
    const int t = threadIdx.x;
    const int nh = blockIdx.y, n = nh >> 4, h = nh & 15;
    const int l0 = blockIdx.x * 64;
    for (int i = t; i < 4096; i += 256)
        Wb[(i >> 6) * 72 + (i & 63)] = (__bf16)Wf[i];
    {
        const int row = t >> 2, seg = (t & 3) * 16;
        const float* src = X + ((size_t)(n * SEQ + l0 + row)) * EMB + h * 64 + seg;
        union { __bf16 b[16]; uint4 u[2]; } tmp;
        #pragma unroll
        for (int jj = 0; jj < 4; ++jj) {
            float4 f = ((const float4*)src)[jj];
            tmp.b[jj*4+0] = (__bf16)f.x; tmp.b[jj*4+1] = (__bf16)f.y;
            tmp.b[jj*4+2] = (__bf16)f.z; tmp.b[jj*4+3] = (__bf16)f.w;
        }
        *(uint4*)&Xb[row * 72 + seg]     = tmp.u[0];
        *(uint4*)&Xb[row * 72 + seg + 8] = tmp.u[1];
    }
    __syncthreads();
    const int w = t >> 6, lane = t & 63, quad = lane >> 4, lr = lane & 15;
    bf16x8 af[2];
    #pragma unroll
    for (int ks = 0; ks < 2; ++ks)
        af[ks] = *(const bf16x8*)&Xb[(w * 16 + lr) * 72 + ks * 32 + quad * 8];
    const f32x4 zero4 = {0.f, 0.f, 0.f, 0.f};
    f32x4 acc[4];
    #pragma unroll
    for (int et = 0; et < 4; ++et) {
        acc[et] = zero4;
        #pragma unroll
        for (int ks = 0; ks < 2; ++ks) {
            bf16x8 bfrag = *(const bf16x8*)&Wb[(et * 16 + lr) * 72 + ks * 32 + quad * 8];
            acc[et] = __builtin_amdgcn_mfma_f32_16x16x32_bf16(af[ks], bfrag, acc[et], 0, 0, 0);
        }
    }
    if (z == 0) {
        #pragma unroll
        for (int et = 0; et < 4; ++et) acc[et] *= QSCALE;
    }
    __syncthreads();   // all waves past their Xb fragment reads (acc dependency)
    if (z < 2) {
        // tile[l][e] then coalesced row store
        #pragma unroll
        for (int et = 0; et < 4; ++et)
            #pragma unroll
            for (int rr = 0; rr < 4; ++rr)
                Xb[(w * 16 + quad * 4 + rr) * 72 + et * 16 + lr] = (__bf16)acc[et][rr];
        __syncthreads();
        const int row = t >> 2, seg = (t & 3) * 16;
        uint4 a = *(uint4*)&Xb[row * 72 + seg];
        uint4 b = *(uint4*)&Xb[row * 72 + seg + 8];
        __bf16* outp = (z == 0) ? qp : kp;
        __bf16* dst = outp + (size_t)nh * 65536 + (size_t)(l0 + row) * 64 + seg;
        *(uint4*)&dst[0] = a;
        *(uint4*)&dst[8] = b;
    } else {
        // tile[e][l] then coalesced row store into (N,H,64,SEQ)
        #pragma unroll
        for (int et = 0; et < 4; ++et)
            #pragma unroll
            for (int rr = 0; rr < 4; ++rr)
                Xb[(et * 16 + lr) * 72 + w * 16 + quad * 4 + rr] = (__bf16)acc[et][rr];
        __syncthreads();
        const int e = t >> 2, seg = (t & 3) * 16;
        uint4 a = *(uint4*)&Xb[e * 72 + seg];
        uint4 b = *(uint4*)&Xb[e * 72 + seg + 8];
        __bf16* dst = vpt + (size_t)nh * 65536 + (size_t)e * SEQ + l0 + seg;
        *(uint4*)&dst[0] = a;
        *(uint4*)&dst[8] = b;
    }
}

// ---------------- Kernel 2: MFMA flash attention, transposed-S, no-max softmax ----------------
// 128 queries per block (2 groups of 64), K/V chunks of 64. 1024 blocks, XCD-pinned per head.
// v2: P stays in registers (cvt_pk + permlane32/16_swap redistribution), K/V staged via
//     global_load_lds into a double buffer with XOR-swizzled source (linear dest, swizzled read).
__global__ __launch_bounds__(256, 4) void attn_mfma(
    const __bf16* __restrict__ qp, const __bf16* __restrict__ kp, const __bf16* __restrict__ vpt,
    const unsigned long long* __restrict__ mp, __bf16* __restrict__ attn_out)
{
    __shared__ __align__(16) __bf16 KV[2][2][64 * 64];   // [buf][0=K,1=V^T][row*64+col], 32 KB
    const int t = threadIdx.x, w = t >> 6, lane = t & 63, quad = lane >> 4, lr = lane & 15;
    const int bid = blockIdx.x;
    const int nh = bid & 127, qg = bid >> 7;       // same head -> same XCD (stride-128 blocks)
    const int n = nh >> 4, h = nh & 15;
    const int q0 = qg * 128;
    const __bf16* Q  = qp  + (size_t)nh * 65536;
    const __bf16* K  = kp  + (size_t)nh * 65536;
    const __bf16* VT = vpt + (size_t)nh * 65536;

    int qrow[2];
    bf16x8 qf[2][2];
    const unsigned long long* mrow[2];
    #pragma unroll
    for (int g = 0; g < 2; ++g) {
        qrow[g] = q0 + g * 64 + w * 16 + lr;
        qf[g][0] = *(const bf16x8*)&Q[(size_t)qrow[g] * 64 + quad * 8];
        qf[g][1] = *(const bf16x8*)&Q[(size_t)qrow[g] * 64 + 32 + quad * 8];
        mrow[g] = mp + ((size_t)n * SEQ + qrow[g]) * 16;
    }

    // staging: thread t covers 16B chunks c=t and c=t+256 of each 8 KB tile.
    // source chunk index is XOR-swizzled by (row&7) so the *read* swizzle lands on linear data.
    const int srow = t >> 3, sc8 = t & 7;
    const int sswz = (sc8 ^ (srow & 7)) * 8;           // element offset of swizzled 16B chunk
    const int kofs = srow * 64 + sswz;                 // K[row][*]; second chunk = +32 rows
    const int vofs = srow * SEQ + sswz;                // V^T[d][*]; second chunk = +32 rows

    auto issue = [&](int kc) {
        const int b = kc & 1;
        __bf16* kb = (__bf16*)&KV[b][0][0];
        __bf16* vb = (__bf16*)&KV[b][1][0];
        const __bf16* ksrc = K  + (size_t)kc * 4096 + kofs;
        const __bf16* vsrc = VT + (size_t)kc * 64   + vofs;
        gld16(ksrc,            kb + t * 8);
        gld16(ksrc + 32 * 64,  kb + t * 8 + 2048);
        gld16(vsrc,            vb + t * 8);
        gld16(vsrc + 32 * SEQ, vb + t * 8 + 2048);
    };

    // per-lane swizzled fragment offsets: chunk j = 4*ks+quad lives at slot j^(lr&7)
    const int s0 = ((quad ^ (lr & 7))) * 8;            // ks=0
    const int s1 = s0 ^ 32;                            // ks=1 (chunk j^4 -> slot offset ^32 elems)

    const f32x4 zero4 = {0.f, 0.f, 0.f, 0.f};
    f32x4 O[2][4];
    #pragma unroll
    for (int g = 0; g < 2; ++g)
        #pragma unroll
        for (int mt = 0; mt < 4; ++mt) O[g][mt] = zero4;
    float l_part[2] = {0.f, 0.f};

    issue(0);
    for (int kc = 0; kc < 16; ++kc) {
        __syncthreads();              // compiler drains vmcnt(0) here: tile kc is in LDS
        if (kc + 1 < 16) issue(kc + 1);   // prefetch next tile into the other buffer
        const unsigned long long mw0 = mrow[0][kc], mw1 = mrow[1][kc];
        const __bf16* Kb = (const __bf16*)&KV[kc & 1][0][0];
        const __bf16* Vb = (const __bf16*)&KV[kc & 1][1][0];

        // S^T = K @ Q^T : col = q (lr), row = key = kt*16 + quad*4 + r.  kf shared across groups.
        f32x4 S[2][4];
        #pragma unroll
        for (int g = 0; g < 2; ++g)
            #pragma unroll
            for (int kt = 0; kt < 4; ++kt) S[g][kt] = zero4;
        __builtin_amdgcn_s_setprio(1);
        #pragma unroll
        for (int kt = 0; kt < 4; ++kt) {
            bf16x8 kf0 = *(const bf16x8*)&Kb[(kt * 16 + lr) * 64 + s0];
            bf16x8 kf1 = *(const bf16x8*)&Kb[(kt * 16 + lr) * 64 + s1];
            S[0][kt] = __builtin_amdgcn_mfma_f32_16x16x32_bf16(kf0, qf[0][0], S[0][kt], 0, 0, 0);
            S[1][kt] = __builtin_amdgcn_mfma_f32_16x16x32_bf16(kf0, qf[1][0], S[1][kt], 0, 0, 0);
            S[0][kt] = __builtin_amdgcn_mfma_f32_16x16x32_bf16(kf1, qf[0][1], S[0][kt], 0, 0, 0);
            S[1][kt] = __builtin_amdgcn_mfma_f32_16x16x32_bf16(kf1, qf[1][1], S[1][kt], 0, 0, 0);
        }
        __builtin_amdgcn_s_setprio(0);

        // masked exp + in-register P^T redistribution into PV B-fragments.
        bf16x8 pf[2][2];
        #pragma unroll
        for (int g = 0; g < 2; ++g) {
            const unsigned long long mword = g ? mw1 : mw0;
            const unsigned int mlo = (unsigned int)(mword >> (quad * 4));
            const unsigned int mhi = (unsigned int)(mword >> (32 + quad * 4));
            float ev[16];
            float lsum = 0.f;
            #pragma unroll
            for (int kt = 0; kt < 4; ++kt)
                #pragma unroll
                for (int r = 0; r < 4; ++r) {
                    unsigned int bits = (kt < 2) ? mlo : mhi;
                    int sh = (kt & 1) * 16 + r;
                    float sv = ((bits >> sh) & 1u) ? S[g][kt][r] : MASKV;
                    float e = EXPD(sv);             // masked -> exp underflows to exactly 0
                    lsum += e;
                    ev[kt * 4 + r] = e;
                }
            l_part[g] += lsum;
            // lane(quad,lr) holds P^T keys 16kt+4quad+{0..3}; B-frag needs keys 32ks+8quad+{0..7}.
            // (d0,d2) = permlane16_swap(permlane32_swap(pk(kt=2ks), pk(kt=2ks+1))), same for hi.
            #pragma unroll
            for (int ks = 0; ks < 2; ++ks) {
                const int ka = (2 * ks) * 4, kb2 = (2 * ks + 1) * 4;
                int d0 = cvtpk_bf16(ev[ka + 0], ev[ka + 1]);
                int d1 = cvtpk_bf16(ev[ka + 2], ev[ka + 3]);
                int d2 = cvtpk_bf16(ev[kb2 + 0], ev[kb2 + 1]);
                int d3 = cvtpk_bf16(ev[kb2 + 2], ev[kb2 + 3]);
                asm("v_permlane32_swap_b32 %0, %1" : "+v"(d0), "+v"(d2));
                asm("v_permlane16_swap_b32 %0, %1" : "+v"(d0), "+v"(d2));
                asm("v_permlane32_swap_b32 %0, %1" : "+v"(d1), "+v"(d3));
                asm("v_permlane16_swap_b32 %0, %1" : "+v"(d1), "+v"(d3));
                union { int di[4]; bf16x8 v; } pb;
                pb.di[0] = d0; pb.di[1] = d1; pb.di[2] = d2; pb.di[3] = d3;
                pf[g][ks] = pb.v;
            }
        }

        // O^T += V^T @ P^T ; V-frags shared across the two q-groups
        __builtin_amdgcn_s_setprio(1);
        #pragma unroll
        for (int ks = 0; ks < 2; ++ks) {
            const int sv = ks ? s1 : s0;
            #pragma unroll
            for (int mt = 0; mt < 4; ++mt) {
                bf16x8 vf = *(const bf16x8*)&Vb[(mt * 16 + lr) * 64 + sv];
                O[0][mt] = __builtin_amdgcn_mfma_f32_16x16x32_bf16(vf, pf[0][ks], O[0][mt], 0, 0, 0);
                O[1][mt] = __builtin_amdgcn_mfma_f32_16x16x32_bf16(vf, pf[1][ks], O[1][mt], 0, 0, 0);
            }
        }
        __builtin_amdgcn_s_setprio(0);
    }
    #pragma unroll
    for (int g = 0; g < 2; ++g) {
        float l = l_part[g];
        l += __shfl_xor(l, 16, 64);
        l += __shfl_xor(l, 32, 64);
        const float linv = 1.0f / l;
        #pragma unroll
        for (int mt = 0; mt < 4; ++mt) {
            union { __bf16 b[4]; uint2 u; } pk;
            #pragma unroll
            for (int r = 0; r < 4; ++r) pk.b[r] = (__bf16)(O[g][mt][r] * linv);
            *(uint2*)&attn_out[((size_t)n * SEQ + qrow[g]) * EMB + h * 64 + mt * 16 + quad * 4] = pk.u;
        }
    }
}

// ---------------- Kernel 3a: Wo f32 -> bf16 ----------------
__global__ __launch_bounds__(256) void cvt_wo(const float* __restrict__ Wo, __bf16* __restrict__ Wob)
{
    int i = blockIdx.x * 256 + threadIdx.x;
    float4 f = *(const float4*)&Wo[(size_t)i * 4];
    union { __bf16 b[4]; uint2 u; } tmp;
    tmp.b[0] = (__bf16)f.x; tmp.b[1] = (__bf16)f.y; tmp.b[2] = (__bf16)f.z; tmp.b[3] = (__bf16)f.w;
    *(uint2*)&Wob[(size_t)i * 4] = tmp.u;
}

// ---------------- Kernel 3b: out = A(8192x1024) @ Wob^T + bo, MFMA, 64x128 tile ----------------
__global__ __launch_bounds__(256, 4) void out_gemm_mfma(
    const __bf16* __restrict__ A, const __bf16* __restrict__ B,
    const float* __restrict__ bo, float* __restrict__ out)
{
    __shared__ __align__(16) __bf16 As[64 * 40];
    __shared__ __align__(16) __bf16 Bs[128 * 40];
    const int t = threadIdx.x, w = t >> 6, lane = t & 63, quad = lane >> 4, lr = lane & 15;
    const int wr = (w >> 1) * 32, wc = (w & 1) * 64;
    const int r0 = blockIdx.y * 64, e0 = blockIdx.x * 128;
    const f32x4 zero4 = {0.f, 0.f, 0.f, 0.f};
    f32x4 acc[2][4];
    #pragma unroll
    for (int mt = 0; mt < 2; ++mt)
        #pragma unroll
        for (int nt = 0; nt < 4; ++nt) acc[mt][nt] = zero4;
    for (int k0 = 0; k0 < 1024; k0 += 32) {
        __syncthreads();
        {
            int row = t >> 2, c8 = t & 3;
            *(uint4*)&As[row * 40 + c8 * 8] =
                *(const uint4*)&A[(size_t)(r0 + row) * EMB + k0 + c8 * 8];
        }
        for (int c = t; c < 512; c += 256) {
            int row = c >> 2, c8 = c & 3;
            *(uint4*)&Bs[row * 40 + c8 * 8] =
                *(const uint4*)&B[(size_t)(e0 + row) * EMB + k0 + c8 * 8];
        }
        __syncthreads();
        bf16x8 af[2], bf[4];
        #pragma unroll
        for (int mt = 0; mt < 2; ++mt)
            af[mt] = *(const bf16x8*)&As[(wr + mt * 16 + lr) * 40 + quad * 8];
        #pragma unroll
        for (int nt = 0; nt < 4; ++nt)
            bf[nt] = *(const bf16x8*)&Bs[(wc + nt * 16 + lr) * 40 + quad * 8];
        #pragma unroll
        for (int mt = 0; mt < 2; ++mt)
            #pragma unroll
            for (int nt = 0; nt < 4; ++nt)
                acc[mt][nt] = __builtin_amdgcn_mfma_f32_16x16x32_bf16(af[mt], bf[nt], acc[mt][nt], 0, 0, 0);
    }
    float bv[4];
    #pragma unroll
    for (int nt = 0; nt < 4; ++nt) bv[nt] = bo[e0 + wc + nt * 16 + lr];
    #pragma unroll
    for (int mt = 0; mt < 2; ++mt)
        #pragma unroll
        for (int nt = 0; nt < 4; ++nt)
            #pragma unroll
            for (int rr = 0; rr < 4; ++rr)
                out[(size_t)(r0 + wr + mt * 16 + quad * 4 + rr) * EMB + e0 + wc + nt * 16 + lr] =
                    acc[mt][nt][rr] + bv[nt];
}

extern "C" void kernel_launch(void* const* d_in, const int* in_sizes, int n_in,
                              void* d_out, int out_size, void* d_ws, size_t ws_size,
                              hipStream_t stream) {
    const float* values = (const float*)d_in[0];
    const float* keys   = (const float*)d_in[1];
    const float* query  = (const float*)d_in[2];
    const int*   mask   = (const int*)d_in[3];
    const float* Wv     = (const float*)d_in[4];
    const float* Wk     = (const float*)d_in[5];
    const float* Wq     = (const float*)d_in[6];
    const float* Wo     = (const float*)d_in[7];
    const float* bo     = (const float*)d_in[8];
    float* out = (float*)d_out;

    const size_t per = (size_t)NB * HEADS * SEQ * HD;  // 8,388,608 elems
    __bf16* qp   = (__bf16*)d_ws;
    __bf16* kp   = qp + per;
    __bf16* vpt  = kp + per;                         // V transposed (N,H,64,SEQ)
    __bf16* attn = vpt + per;                        // (N*SEQ, EMB)
    __bf16* Wob  = attn + (size_t)NB * SEQ * EMB;
    unsigned long long* maskp = (unsigned long long*)(Wob + (size_t)EMB * EMB);

    mask_pack<<<dim3(SEQ, NB), 256, 0, stream>>>(mask, maskp);
    proj_mfma<<<dim3(16, 128, 3), 256, 0, stream>>>(query, keys, values, Wq, Wk, Wv, qp, kp, vpt);
    cvt_wo<<<1024, 256, 0, stream>>>(Wo, Wob);
    attn_mfma<<<1024, 256, 0, stream>>>(qp, kp, vpt, maskp, attn);
    out_gemm_mfma<<<dim3(EMB / 128, NB * SEQ / 64), 256, 0, stream>>>(attn, Wob, bo, out);
}

// Round 2
// 278.172 us; speedup vs baseline: 1.0177x; 1.0006x over previous
//
#include <hip/hip_runtime.h>
#include <hip/hip_bf16.h>

using bf16x8 = __attribute__((ext_vector_type(8))) __bf16;
using f32x4  = __attribute__((ext_vector_type(4))) float;
using f32x2  = __attribute__((ext_vector_type(2))) float;

#define NB 8
#define SEQ 1024
#define HEADS 16
#define HD 64
#define EMB 1024

// exp domain: prefer native exp2 (one v_exp_f32), fold log2(e) into the Q prescale.
#if __has_builtin(__builtin_amdgcn_exp2f)
  #define EXPD(x) __builtin_amdgcn_exp2f(x)
  #define QSCALE  0.04508422f    /* (1/32) * log2(e) */
#else
  #define EXPD(x) __expf(x)
  #define QSCALE  0.03125f
#endif

__device__ __forceinline__ int cvtpk_bf16(float lo, float hi) {
    int r;
    asm("v_cvt_pk_bf16_f32 %0, %1, %2" : "=v"(r) : "v"(lo), "v"(hi));
    return r;
}

// e where mask-bit of this lane is set, else 0.0f. m is wave-uniform (SGPR pair).
__device__ __forceinline__ float sel0(float e, unsigned long long m) {
    float r;
    asm("v_cndmask_b32 %0, 0, %1, %2" : "=v"(r) : "v"(e), "s"(m));
    return r;
}

__device__ __forceinline__ void gld16(const __bf16* g, __bf16* l) {
    __builtin_amdgcn_global_load_lds((const __attribute__((address_space(1))) void*)g,
                                     (__attribute__((address_space(3))) void*)l, 16, 0, 0);
}

// ---------------- Kernel 0: permute mask into per-wave ballot words ----------------
// mq[n][qg][w][g][kc][kt*4+r] : u64, bit l = (mask[n][qg*128+g*64+w*16+(l&15)][kc*64+kt*16+(l>>4)*4+r] != 0)
// This is exactly the lane-mask attn's v_cndmask needs; shared across all 16 heads.
__global__ __launch_bounds__(256) void mask_perm(const int* __restrict__ mask,
                                                 unsigned long long* __restrict__ mq)
{
    const int t = threadIdx.x, w = t >> 6, lane = t & 63, quad = lane >> 4, lq = lane & 15;
    const int bx = blockIdx.x;                 // qg(8) x g(2) x kc(16)
    const int n = blockIdx.y;
    const int qg = bx >> 5, g = (bx >> 4) & 1, kc = bx & 15;
    const int q = qg * 128 + g * 64 + w * 16 + lq;
    const int* mrow = mask + ((size_t)n * SEQ + q) * SEQ + kc * 64 + quad * 4;
    unsigned long long* dst = mq + ((size_t)(((n * 8 + qg) * 4 + w) * 2 + g) * 16 + kc) * 16;
    #pragma unroll
    for (int kt = 0; kt < 4; ++kt)
        #pragma unroll
        for (int r = 0; r < 4; ++r) {
            unsigned long long b = __ballot(mrow[kt * 16 + r] != 0);
            if (lane == 0) dst[kt * 4 + r] = b;
        }
}

// ---------------- Kernel 1: per-head projection, MFMA ----------------
// z=0: Q out (N,H,SEQ,64), pre-scaled by QSCALE.  z=1: K out.  z=2: V out transposed (N,H,64,SEQ).
__global__ __launch_bounds__(256, 4) void proj_mfma(
    const float* __restrict__ q_in, const float* __restrict__ k_in, const float* __restrict__ v_in,
    const float* __restrict__ Wq, const float* __restrict__ Wk, const float* __restrict__ Wv,
    __bf16* __restrict__ qp, __bf16* __restrict__ kp, __bf16* __restrict__ vpt)
{
    const int z = blockIdx.z;
    const float* X  = (z == 0) ? q_in : (z == 1) ? k_in : v_in;
    const float* Wf = (z == 0) ? Wq   : (z == 1) ? Wk   : Wv;

    __shared__ __align__(16) __bf16 Wb[64 * 72];  // Wb[e][d]
    __shared__ __align__(16) __bf16 Xb[64 * 72];  // Xb[l][d]; reused as output tile
    const int t = threadIdx.x;
    const int nh = blockIdx.y, n = nh >> 4, h = nh & 15;
    const int l0 = blockIdx.x * 64;
    for (int i = t; i < 4096; i += 256)
        Wb[(i >> 6) * 72 + (i & 63)] = (__bf16)Wf[i];
    {
        const int row = t >> 2, seg = (t & 3) * 16;
        const float* src = X + ((size_t)(n * SEQ + l0 + row)) * EMB + h * 64 + seg;
        union { __bf16 b[16]; uint4 u[2]; } tmp;
        #pragma unroll
        for (int jj = 0; jj < 4; ++jj) {
            float4 f = ((const float4*)src)[jj];
            tmp.b[jj*4+0] = (__bf16)f.x; tmp.b[jj*4+1] = (__bf16)f.y;
            tmp.b[jj*4+2] = (__bf16)f.z; tmp.b[jj*4+3] = (__bf16)f.w;
        }
        *(uint4*)&Xb[row * 72 + seg]     = tmp.u[0];
        *(uint4*)&Xb[row * 72 + seg + 8] = tmp.u[1];
    }
    __syncthreads();
    const int w = t >> 6, lane = t & 63, quad = lane >> 4, lr = lane & 15;
    bf16x8 af[2];
    #pragma unroll
    for (int ks = 0; ks < 2; ++ks)
        af[ks] = *(const bf16x8*)&Xb[(w * 16 + lr) * 72 + ks * 32 + quad * 8];
    const f32x4 zero4 = {0.f, 0.f, 0.f, 0.f};
    f32x4 acc[4];
    #pragma unroll
    for (int et = 0; et < 4; ++et) {
        acc[et] = zero4;
        #pragma unroll
        for (int ks = 0; ks < 2; ++ks) {
            bf16x8 bfrag = *(const bf16x8*)&Wb[(et * 16 + lr) * 72 + ks * 32 + quad * 8];
            acc[et] = __builtin_amdgcn_mfma_f32_16x16x32_bf16(af[ks], bfrag, acc[et], 0, 0, 0);
        }
    }
    if (z == 0) {
        #pragma unroll
        for (int et = 0; et < 4; ++et) acc[et] *= QSCALE;
    }
    __syncthreads();   // all waves past their Xb fragment reads (acc dependency)
    if (z < 2) {
        // tile[l][e] then coalesced row store
        #pragma unroll
        for (int et = 0; et < 4; ++et)
            #pragma unroll
            for (int rr = 0; rr < 4; ++rr)
                Xb[(w * 16 + quad * 4 + rr) * 72 + et * 16 + lr] = (__bf16)acc[et][rr];
        __syncthreads();
        const int row = t >> 2, seg = (t & 3) * 16;
        uint4 a = *(uint4*)&Xb[row * 72 + seg];
        uint4 b = *(uint4*)&Xb[row * 72 + seg + 8];
        __bf16* outp = (z == 0) ? qp : kp;
        __bf16* dst = outp + (size_t)nh * 65536 + (size_t)(l0 + row) * 64 + seg;
        *(uint4*)&dst[0] = a;
        *(uint4*)&dst[8] = b;
    } else {
        // tile[e][l] then coalesced row store into (N,H,64,SEQ)
        #pragma unroll
        for (int et = 0; et < 4; ++et)
            #pragma unroll
            for (int rr = 0; rr < 4; ++rr)
                Xb[(et * 16 + lr) * 72 + w * 16 + quad * 4 + rr] = (__bf16)acc[et][rr];
        __syncthreads();
        const int e = t >> 2, seg = (t & 3) * 16;
        uint4 a = *(uint4*)&Xb[e * 72 + seg];
        uint4 b = *(uint4*)&Xb[e * 72 + seg + 8];
        __bf16* dst = vpt + (size_t)nh * 65536 + (size_t)e * SEQ + l0 + seg;
        *(uint4*)&dst[0] = a;
        *(uint4*)&dst[8] = b;
    }
}

// ---------------- Kernel 2: MFMA flash attention, transposed-S, no-max softmax ----------------
// 128 queries per block (2 groups of 64), K/V chunks of 64. 1024 blocks, XCD-pinned per head.
// v3: mask applied as wave-uniform SGPR lane-mask in ONE v_cndmask per element (after exp);
//     lsum accumulated as f32x2 (v_pk_add_f32); P stays in registers (cvt_pk + permlane swaps);
//     K/V staged via global_load_lds double buffer with XOR-swizzled source.
__global__ __launch_bounds__(256, 4) void attn_mfma(
    const __bf16* __restrict__ qp, const __bf16* __restrict__ kp, const __bf16* __restrict__ vpt,
    const unsigned long long* __restrict__ mq, __bf16* __restrict__ attn_out)
{
    __shared__ __align__(16) __bf16 KV[2][2][64 * 64];   // [buf][0=K,1=V^T][row*64+col], 32 KB
    const int t = threadIdx.x, w = t >> 6, lane = t & 63, quad = lane >> 4, lr = lane & 15;
    const int bid = blockIdx.x;
    const int nh = bid & 127, qg = bid >> 7;       // same head -> same XCD (stride-128 blocks)
    const int n = nh >> 4, h = nh & 15;
    const int q0 = qg * 128;
    const __bf16* Q  = qp  + (size_t)nh * 65536;
    const __bf16* K  = kp  + (size_t)nh * 65536;
    const __bf16* VT = vpt + (size_t)nh * 65536;

    // wave-uniform base for the pre-permuted mask words (shared across heads)
    const int wu = __builtin_amdgcn_readfirstlane(w);
    const unsigned long long* mq_w = mq + (size_t)((n * 8 + qg) * 4 + wu) * 512;

    int qrow[2];
    bf16x8 qf[2][2];
    #pragma unroll
    for (int g = 0; g < 2; ++g) {
        qrow[g] = q0 + g * 64 + w * 16 + lr;
        qf[g][0] = *(const bf16x8*)&Q[(size_t)qrow[g] * 64 + quad * 8];
        qf[g][1] = *(const bf16x8*)&Q[(size_t)qrow[g] * 64 + 32 + quad * 8];
    }

    // staging: thread t covers 16B chunks c=t and c=t+256 of each 8 KB tile.
    // source chunk index is XOR-swizzled by (row&7) so the *read* swizzle lands on linear data.
    const int srow = t >> 3, sc8 = t & 7;
    const int sswz = (sc8 ^ (srow & 7)) * 8;           // element offset of swizzled 16B chunk
    const int kofs = srow * 64 + sswz;                 // K[row][*]; second chunk = +32 rows
    const int vofs = srow * SEQ + sswz;                // V^T[d][*]; second chunk = +32 rows

    auto issue = [&](int kc) {
        const int b = kc & 1;
        __bf16* kb = (__bf16*)&KV[b][0][0];
        __bf16* vb = (__bf16*)&KV[b][1][0];
        const __bf16* ksrc = K  + (size_t)kc * 4096 + kofs;
        const __bf16* vsrc = VT + (size_t)kc * 64   + vofs;
        gld16(ksrc,            kb + t * 8);
        gld16(ksrc + 32 * 64,  kb + t * 8 + 2048);
        gld16(vsrc,            vb + t * 8);
        gld16(vsrc + 32 * SEQ, vb + t * 8 + 2048);
    };

    // per-lane swizzled fragment offsets: chunk j = 4*ks+quad lives at slot j^(lr&7)
    const int s0 = ((quad ^ (lr & 7))) * 8;            // ks=0
    const int s1 = s0 ^ 32;                            // ks=1 (chunk j^4 -> slot offset ^32 elems)

    const f32x4 zero4 = {0.f, 0.f, 0.f, 0.f};
    f32x4 O[2][4];
    #pragma unroll
    for (int g = 0; g < 2; ++g)
        #pragma unroll
        for (int mt = 0; mt < 4; ++mt) O[g][mt] = zero4;
    f32x2 lp2[2] = {{0.f, 0.f}, {0.f, 0.f}};

    issue(0);
    for (int kc = 0; kc < 16; ++kc) {
        __syncthreads();              // compiler drains vmcnt(0) here: tile kc is in LDS
        if (kc + 1 < 16) issue(kc + 1);   // prefetch next tile into the other buffer
        const __bf16* Kb = (const __bf16*)&KV[kc & 1][0][0];
        const __bf16* Vb = (const __bf16*)&KV[kc & 1][1][0];

        // S^T = K @ Q^T : col = q (lr), row = key = kt*16 + quad*4 + r.  kf shared across groups.
        f32x4 S[2][4];
        #pragma unroll
        for (int g = 0; g < 2; ++g)
            #pragma unroll
            for (int kt = 0; kt < 4; ++kt) S[g][kt] = zero4;
        __builtin_amdgcn_s_setprio(1);
        #pragma unroll
        for (int kt = 0; kt < 4; ++kt) {
            bf16x8 kf0 = *(const bf16x8*)&Kb[(kt * 16 + lr) * 64 + s0];
            bf16x8 kf1 = *(const bf16x8*)&Kb[(kt * 16 + lr) * 64 + s1];
            S[0][kt] = __builtin_amdgcn_mfma_f32_16x16x32_bf16(kf0, qf[0][0], S[0][kt], 0, 0, 0);
            S[1][kt] = __builtin_amdgcn_mfma_f32_16x16x32_bf16(kf0, qf[1][0], S[1][kt], 0, 0, 0);
            S[0][kt] = __builtin_amdgcn_mfma_f32_16x16x32_bf16(kf1, qf[0][1], S[0][kt], 0, 0, 0);
            S[1][kt] = __builtin_amdgcn_mfma_f32_16x16x32_bf16(kf1, qf[1][1], S[1][kt], 0, 0, 0);
        }
        __builtin_amdgcn_s_setprio(0);

        // exp (unconditional, |S|<~3 so no overflow) -> single v_cndmask with SGPR lane-mask
        // -> f32x2 lsum -> in-register P^T redistribution into PV B-fragments.
        bf16x8 pf[2][2];
        #pragma unroll
        for (int g = 0; g < 2; ++g) {
            const unsigned long long* Mg = mq_w + g * 256 + kc * 16;
            float ev[16];
            #pragma unroll
            for (int kt = 0; kt < 4; ++kt)
                #pragma unroll
                for (int r = 0; r < 4; ++r)
                    ev[kt * 4 + r] = sel0(EXPD(S[g][kt][r]), Mg[kt * 4 + r]);
            #pragma unroll
            for (int i = 0; i < 8; ++i) {
                f32x2 p2 = {ev[2 * i], ev[2 * i + 1]};
                lp2[g] += p2;
            }
            // lane(quad,lr) holds P^T keys 16kt+4quad+{0..3}; B-frag needs keys 32ks+8quad+{0..7}.
            // (d0,d2) = permlane16_swap(permlane32_swap(pk(kt=2ks), pk(kt=2ks+1))), same for hi.
            #pragma unroll
            for (int ks = 0; ks < 2; ++ks) {
                const int ka = (2 * ks) * 4, kb2 = (2 * ks + 1) * 4;
                int d0 = cvtpk_bf16(ev[ka + 0], ev[ka + 1]);
                int d1 = cvtpk_bf16(ev[ka + 2], ev[ka + 3]);
                int d2 = cvtpk_bf16(ev[kb2 + 0], ev[kb2 + 1]);
                int d3 = cvtpk_bf16(ev[kb2 + 2], ev[kb2 + 3]);
                asm("v_permlane32_swap_b32 %0, %1" : "+v"(d0), "+v"(d2));
                asm("v_permlane16_swap_b32 %0, %1" : "+v"(d0), "+v"(d2));
                asm("v_permlane32_swap_b32 %0, %1" : "+v"(d1), "+v"(d3));
                asm("v_permlane16_swap_b32 %0, %1" : "+v"(d1), "+v"(d3));
                union { int di[4]; bf16x8 v; } pb;
                pb.di[0] = d0; pb.di[1] = d1; pb.di[2] = d2; pb.di[3] = d3;
                pf[g][ks] = pb.v;
            }
        }

        // O^T += V^T @ P^T ; V-frags shared across the two q-groups
        __builtin_amdgcn_s_setprio(1);
        #pragma unroll
        for (int ks = 0; ks < 2; ++ks) {
            const int sv = ks ? s1 : s0;
            #pragma unroll
            for (int mt = 0; mt < 4; ++mt) {
                bf16x8 vf = *(const bf16x8*)&Vb[(mt * 16 + lr) * 64 + sv];
                O[0][mt] = __builtin_amdgcn_mfma_f32_16x16x32_bf16(vf, pf[0][ks], O[0][mt], 0, 0, 0);
                O[1][mt] = __builtin_amdgcn_mfma_f32_16x16x32_bf16(vf, pf[1][ks], O[1][mt], 0, 0, 0);
            }
        }
        __builtin_amdgcn_s_setprio(0);
    }
    #pragma unroll
    for (int g = 0; g < 2; ++g) {
        float l = lp2[g].x + lp2[g].y;
        l += __shfl_xor(l, 16, 64);
        l += __shfl_xor(l, 32, 64);
        const float linv = 1.0f / l;
        #pragma unroll
        for (int mt = 0; mt < 4; ++mt) {
            union { __bf16 b[4]; uint2 u; } pk;
            #pragma unroll
            for (int r = 0; r < 4; ++r) pk.b[r] = (__bf16)(O[g][mt][r] * linv);
            *(uint2*)&attn_out[((size_t)n * SEQ + qrow[g]) * EMB + h * 64 + mt * 16 + quad * 4] = pk.u;
        }
    }
}

// ---------------- Kernel 3a: Wo f32 -> bf16 ----------------
__global__ __launch_bounds__(256) void cvt_wo(const float* __restrict__ Wo, __bf16* __restrict__ Wob)
{
    int i = blockIdx.x * 256 + threadIdx.x;
    float4 f = *(const float4*)&Wo[(size_t)i * 4];
    union { __bf16 b[4]; uint2 u; } tmp;
    tmp.b[0] = (__bf16)f.x; tmp.b[1] = (__bf16)f.y; tmp.b[2] = (__bf16)f.z; tmp.b[3] = (__bf16)f.w;
    *(uint2*)&Wob[(size_t)i * 4] = tmp.u;
}

// ---------------- Kernel 3b: out = A(8192x1024) @ Wob^T + bo, MFMA, 64x128 tile ----------------
__global__ __launch_bounds__(256, 4) void out_gemm_mfma(
    const __bf16* __restrict__ A, const __bf16* __restrict__ B,
    const float* __restrict__ bo, float* __restrict__ out)
{
    __shared__ __align__(16) __bf16 As[64 * 40];
    __shared__ __align__(16) __bf16 Bs[128 * 40];
    const int t = threadIdx.x, w = t >> 6, lane = t & 63, quad = lane >> 4, lr = lane & 15;
    const int wr = (w >> 1) * 32, wc = (w & 1) * 64;
    const int r0 = blockIdx.y * 64, e0 = blockIdx.x * 128;
    const f32x4 zero4 = {0.f, 0.f, 0.f, 0.f};
    f32x4 acc[2][4];
    #pragma unroll
    for (int mt = 0; mt < 2; ++mt)
        #pragma unroll
        for (int nt = 0; nt < 4; ++nt) acc[mt][nt] = zero4;
    for (int k0 = 0; k0 < 1024; k0 += 32) {
        __syncthreads();
        {
            int row = t >> 2, c8 = t & 3;
            *(uint4*)&As[row * 40 + c8 * 8] =
                *(const uint4*)&A[(size_t)(r0 + row) * EMB + k0 + c8 * 8];
        }
        for (int c = t; c < 512; c += 256) {
            int row = c >> 2, c8 = c & 3;
            *(uint4*)&Bs[row * 40 + c8 * 8] =
                *(const uint4*)&B[(size_t)(e0 + row) * EMB + k0 + c8 * 8];
        }
        __syncthreads();
        bf16x8 af[2], bf[4];
        #pragma unroll
        for (int mt = 0; mt < 2; ++mt)
            af[mt] = *(const bf16x8*)&As[(wr + mt * 16 + lr) * 40 + quad * 8];
        #pragma unroll
        for (int nt = 0; nt < 4; ++nt)
            bf[nt] = *(const bf16x8*)&Bs[(wc + nt * 16 + lr) * 40 + quad * 8];
        #pragma unroll
        for (int mt = 0; mt < 2; ++mt)
            #pragma unroll
            for (int nt = 0; nt < 4; ++nt)
                acc[mt][nt] = __builtin_amdgcn_mfma_f32_16x16x32_bf16(af[mt], bf[nt], acc[mt][nt], 0, 0, 0);
    }
    float bv[4];
    #pragma unroll
    for (int nt = 0; nt < 4; ++nt) bv[nt] = bo[e0 + wc + nt * 16 + lr];
    #pragma unroll
    for (int mt = 0; mt < 2; ++mt)
        #pragma unroll
        for (int nt = 0; nt < 4; ++nt)
            #pragma unroll
            for (int rr = 0; rr < 4; ++rr)
                out[(size_t)(r0 + wr + mt * 16 + quad * 4 + rr) * EMB + e0 + wc + nt * 16 + lr] =
                    acc[mt][nt][rr] + bv[nt];
}

extern "C" void kernel_launch(void* const* d_in, const int* in_sizes, int n_in,
                              void* d_out, int out_size, void* d_ws, size_t ws_size,
                              hipStream_t stream) {
    const float* values = (const float*)d_in[0];
    const float* keys   = (const float*)d_in[1];
    const float* query  = (const float*)d_in[2];
    const int*   mask   = (const int*)d_in[3];
    const float* Wv     = (const float*)d_in[4];
    const float* Wk     = (const float*)d_in[5];
    const float* Wq     = (const float*)d_in[6];
    const float* Wo     = (const float*)d_in[7];
    const float* bo     = (const float*)d_in[8];
    float* out = (float*)d_out;

    const size_t per = (size_t)NB * HEADS * SEQ * HD;  // 8,388,608 elems
    __bf16* qp   = (__bf16*)d_ws;
    __bf16* kp   = qp + per;
    __bf16* vpt  = kp + per;                         // V transposed (N,H,64,SEQ)
    __bf16* attn = vpt + per;                        // (N*SEQ, EMB)
    __bf16* Wob  = attn + (size_t)NB * SEQ * EMB;
    unsigned long long* maskq = (unsigned long long*)(Wob + (size_t)EMB * EMB);  // 1 MB

    mask_perm<<<dim3(256, NB), 256, 0, stream>>>(mask, maskq);
    proj_mfma<<<dim3(16, 128, 3), 256, 0, stream>>>(query, keys, values, Wq, Wk, Wv, qp, kp, vpt);
    cvt_wo<<<1024, 256, 0, stream>>>(Wo, Wob);
    attn_mfma<<<1024, 256, 0, stream>>>(qp, kp, vpt, maskq, attn);
    out_gemm_mfma<<<dim3(EMB / 128, NB * SEQ / 64), 256, 0, stream>>>(attn, Wob, bo, out);
}

// Round 3
// 254.698 us; speedup vs baseline: 1.1115x; 1.0922x over previous
//
#include <hip/hip_runtime.h>
#include <hip/hip_bf16.h>

using bf16x8 = __attribute__((ext_vector_type(8))) __bf16;
using f32x4  = __attribute__((ext_vector_type(4))) float;

#define NB 8
#define SEQ 1024
#define HEADS 16
#define HD 64
#define EMB 1024

// exp domain: prefer native exp2 (one v_exp_f32), fold log2(e) into the Q prescale.
#if __has_builtin(__builtin_amdgcn_exp2f)
  #define EXPD(x) __builtin_amdgcn_exp2f(x)
  #define QSCALE  0.04508422f    /* (1/32) * log2(e) */
#else
  #define EXPD(x) __expf(x)
  #define QSCALE  0.03125f
#endif

__device__ __forceinline__ int cvtpk_bf16(float lo, float hi) {
    int r;
    asm("v_cvt_pk_bf16_f32 %0, %1, %2" : "=v"(r) : "v"(lo), "v"(hi));
    return r;
}

// e where mask-bit of this lane is set, else 0.0f. m is wave-uniform (SGPR pair).
__device__ __forceinline__ float sel0(float e, unsigned long long m) {
    float r;
    asm("v_cndmask_b32 %0, 0, %1, %2" : "=v"(r) : "v"(e), "s"(m));
    return r;
}

__device__ __forceinline__ void gld16(const __bf16* g, __bf16* l) {
    __builtin_amdgcn_global_load_lds((const __attribute__((address_space(1))) void*)g,
                                     (__attribute__((address_space(3))) void*)l, 16, 0, 0);
}

// ---------------- Kernel 0: permute mask into per-wave ballot words (coalesced) ----------------
// mq word (n,qg,w,g,kc,kt*4+r): bit l = (mask[n][qg*128+g*64+w*16+(l&15)][kc*64+kt*16+(l>>4)*4+r] != 0)
// v2: coalesced uint4 tile load -> LDS [128][68] -> ballots from LDS (2-way conflicts only).
__global__ __launch_bounds__(256) void mask_perm(const int* __restrict__ mask,
                                                 unsigned long long* __restrict__ mq)
{
    __shared__ __align__(16) int Ms[128 * 68];
    const int t = threadIdx.x, w = t >> 6, lane = t & 63, quad = lane >> 4, lq = lane & 15;
    const int n = blockIdx.y;
    const int qg = blockIdx.x >> 4, kc = blockIdx.x & 15;
    const int* src = mask + ((size_t)n * SEQ + qg * 128) * SEQ + kc * 64;
    // 128 rows x 64 ints, 16 uint4 per row, 2048 chunks over 256 threads
    #pragma unroll
    for (int i = 0; i < 8; ++i) {
        const int c = t + i * 256, row = c >> 4, seg = c & 15;
        uint4 v = *(const uint4*)&src[(size_t)row * SEQ + seg * 4];
        *(uint4*)&Ms[row * 68 + seg * 4] = v;
    }
    __syncthreads();
    #pragma unroll
    for (int g = 0; g < 2; ++g) {
        const int row = (g * 64 + w * 16 + lq) * 68 + quad * 4;
        unsigned long long* dst = mq + ((size_t)(((n * 8 + qg) * 4 + w) * 2 + g) * 16 + kc) * 16;
        #pragma unroll
        for (int kt = 0; kt < 4; ++kt)
            #pragma unroll
            for (int r = 0; r < 4; ++r) {
                unsigned long long b = __ballot(Ms[row + kt * 16 + r] != 0);
                if (lane == 0) dst[kt * 4 + r] = b;
            }
    }
}

// ---------------- Kernel 1: per-head projection, MFMA ----------------
// z=0: Q out (N,H,SEQ,64), pre-scaled by QSCALE.  z=1: K out.  z=2: V out transposed (N,H,64,SEQ).
__global__ __launch_bounds__(256, 4) void proj_mfma(
    const float* __restrict__ q_in, const float* __restrict__ k_in, const float* __restrict__ v_in,
    const float* __restrict__ Wq, const float* __restrict__ Wk, const float* __restrict__ Wv,
    __bf16* __restrict__ qp, __bf16* __restrict__ kp, __bf16* __restrict__ vpt)
{
    const int z = blockIdx.z;
    const float* X  = (z == 0) ? q_in : (z == 1) ? k_in : v_in;
    const float* Wf = (z == 0) ? Wq   : (z == 1) ? Wk   : Wv;

    __shared__ __align__(16) __bf16 Wb[64 * 72];  // Wb[e][d]
    __shared__ __align__(16) __bf16 Xb[64 * 72];  // Xb[l][d]; reused as output tile
    const int t = threadIdx.x;
    const int nh = blockIdx.y, n = nh >> 4, h = nh & 15;
    const int l0 = blockIdx.x * 64;
    for (int i = t; i < 4096; i += 256)
        Wb[(i >> 6) * 72 + (i & 63)] = (__bf16)Wf[i];
    {
        const int row = t >> 2, seg = (t & 3) * 16;
        const float* src = X + ((size_t)(n * SEQ + l0 + row)) * EMB + h * 64 + seg;
        union { __bf16 b[16]; uint4 u[2]; } tmp;
        #pragma unroll
        for (int jj = 0; jj < 4; ++jj) {
            float4 f = ((const float4*)src)[jj];
            tmp.b[jj*4+0] = (__bf16)f.x; tmp.b[jj*4+1] = (__bf16)f.y;
            tmp.b[jj*4+2] = (__bf16)f.z; tmp.b[jj*4+3] = (__bf16)f.w;
        }
        *(uint4*)&Xb[row * 72 + seg]     = tmp.u[0];
        *(uint4*)&Xb[row * 72 + seg + 8] = tmp.u[1];
    }
    __syncthreads();
    const int w = t >> 6, lane = t & 63, quad = lane >> 4, lr = lane & 15;
    bf16x8 af[2];
    #pragma unroll
    for (int ks = 0; ks < 2; ++ks)
        af[ks] = *(const bf16x8*)&Xb[(w * 16 + lr) * 72 + ks * 32 + quad * 8];
    const f32x4 zero4 = {0.f, 0.f, 0.f, 0.f};
    f32x4 acc[4];
    #pragma unroll
    for (int et = 0; et < 4; ++et) {
        acc[et] = zero4;
        #pragma unroll
        for (int ks = 0; ks < 2; ++ks) {
            bf16x8 bfrag = *(const bf16x8*)&Wb[(et * 16 + lr) * 72 + ks * 32 + quad * 8];
            acc[et] = __builtin_amdgcn_mfma_f32_16x16x32_bf16(af[ks], bfrag, acc[et], 0, 0, 0);
        }
    }
    if (z == 0) {
        #pragma unroll
        for (int et = 0; et < 4; ++et) acc[et] *= QSCALE;
    }
    __syncthreads();   // all waves past their Xb fragment reads (acc dependency)
    if (z < 2) {
        // tile[l][e] then coalesced row store
        #pragma unroll
        for (int et = 0; et < 4; ++et)
            #pragma unroll
            for (int rr = 0; rr < 4; ++rr)
                Xb[(w * 16 + quad * 4 + rr) * 72 + et * 16 + lr] = (__bf16)acc[et][rr];
        __syncthreads();
        const int row = t >> 2, seg = (t & 3) * 16;
        uint4 a = *(uint4*)&Xb[row * 72 + seg];
        uint4 b = *(uint4*)&Xb[row * 72 + seg + 8];
        __bf16* outp = (z == 0) ? qp : kp;
        __bf16* dst = outp + (size_t)nh * 65536 + (size_t)(l0 + row) * 64 + seg;
        *(uint4*)&dst[0] = a;
        *(uint4*)&dst[8] = b;
    } else {
        // tile[e][l] then coalesced row store into (N,H,64,SEQ)
        #pragma unroll
        for (int et = 0; et < 4; ++et)
            #pragma unroll
            for (int rr = 0; rr < 4; ++rr)
                Xb[(et * 16 + lr) * 72 + w * 16 + quad * 4 + rr] = (__bf16)acc[et][rr];
        __syncthreads();
        const int e = t >> 2, seg = (t & 3) * 16;
        uint4 a = *(uint4*)&Xb[e * 72 + seg];
        uint4 b = *(uint4*)&Xb[e * 72 + seg + 8];
        __bf16* dst = vpt + (size_t)nh * 65536 + (size_t)e * SEQ + l0 + seg;
        *(uint4*)&dst[0] = a;
        *(uint4*)&dst[8] = b;
    }
}

// ---------------- Kernel 2: MFMA flash attention, transposed-S, no-max softmax ----------------
// 128 queries per block (2 groups of 64), K/V chunks of 64. 1024 blocks, XCD-pinned per head.
// v4: l computed on the MFMA pipe (all-ones A-fragment against pf), first QK MFMA takes C=0
//     directly (no S zero-init movs); mask as SGPR lane-mask cndmask; P in registers.
__global__ __launch_bounds__(256, 4) void attn_mfma(
    const __bf16* __restrict__ qp, const __bf16* __restrict__ kp, const __bf16* __restrict__ vpt,
    const unsigned long long* __restrict__ mq, __bf16* __restrict__ attn_out)
{
    __shared__ __align__(16) __bf16 KV[2][2][64 * 64];   // [buf][0=K,1=V^T][row*64+col], 32 KB
    const int t = threadIdx.x, w = t >> 6, lane = t & 63, quad = lane >> 4, lr = lane & 15;
    const int bid = blockIdx.x;
    const int nh = bid & 127, qg = bid >> 7;       // same head -> same XCD (stride-128 blocks)
    const int n = nh >> 4, h = nh & 15;
    const int q0 = qg * 128;
    const __bf16* Q  = qp  + (size_t)nh * 65536;
    const __bf16* K  = kp  + (size_t)nh * 65536;
    const __bf16* VT = vpt + (size_t)nh * 65536;

    // wave-uniform base for the pre-permuted mask words (shared across heads)
    const int wu = __builtin_amdgcn_readfirstlane(w);
    const unsigned long long* mq_w = mq + (size_t)((n * 8 + qg) * 4 + wu) * 512;

    int qrow[2];
    bf16x8 qf[2][2];
    #pragma unroll
    for (int g = 0; g < 2; ++g) {
        qrow[g] = q0 + g * 64 + w * 16 + lr;
        qf[g][0] = *(const bf16x8*)&Q[(size_t)qrow[g] * 64 + quad * 8];
        qf[g][1] = *(const bf16x8*)&Q[(size_t)qrow[g] * 64 + 32 + quad * 8];
    }

    // all-ones A fragment: Lacc[g] = ones(16x32) @ P^T accumulates column sums of P^T = l per q.
    bf16x8 onesf;
    #pragma unroll
    for (int i = 0; i < 8; ++i) onesf[i] = (__bf16)1.0f;

    // staging: thread t covers 16B chunks c=t and c=t+256 of each 8 KB tile.
    // source chunk index is XOR-swizzled by (row&7) so the *read* swizzle lands on linear data.
    const int srow = t >> 3, sc8 = t & 7;
    const int sswz = (sc8 ^ (srow & 7)) * 8;           // element offset of swizzled 16B chunk
    const int kofs = srow * 64 + sswz;                 // K[row][*]; second chunk = +32 rows
    const int vofs = srow * SEQ + sswz;                // V^T[d][*]; second chunk = +32 rows

    auto issue = [&](int kc) {
        const int b = kc & 1;
        __bf16* kb = (__bf16*)&KV[b][0][0];
        __bf16* vb = (__bf16*)&KV[b][1][0];
        const __bf16* ksrc = K  + (size_t)kc * 4096 + kofs;
        const __bf16* vsrc = VT + (size_t)kc * 64   + vofs;
        gld16(ksrc,            kb + t * 8);
        gld16(ksrc + 32 * 64,  kb + t * 8 + 2048);
        gld16(vsrc,            vb + t * 8);
        gld16(vsrc + 32 * SEQ, vb + t * 8 + 2048);
    };

    // per-lane swizzled fragment offsets: chunk j = 4*ks+quad lives at slot j^(lr&7)
    const int s0 = ((quad ^ (lr & 7))) * 8;            // ks=0
    const int s1 = s0 ^ 32;                            // ks=1 (chunk j^4 -> slot offset ^32 elems)

    const f32x4 zero4 = {0.f, 0.f, 0.f, 0.f};
    f32x4 O[2][4];
    f32x4 Lacc[2];
    #pragma unroll
    for (int g = 0; g < 2; ++g) {
        Lacc[g] = zero4;
        #pragma unroll
        for (int mt = 0; mt < 4; ++mt) O[g][mt] = zero4;
    }

    issue(0);
    for (int kc = 0; kc < 16; ++kc) {
        __syncthreads();              // compiler drains vmcnt(0) here: tile kc is in LDS
        if (kc + 1 < 16) issue(kc + 1);   // prefetch next tile into the other buffer
        const __bf16* Kb = (const __bf16*)&KV[kc & 1][0][0];
        const __bf16* Vb = (const __bf16*)&KV[kc & 1][1][0];

        // S^T = K @ Q^T : col = q (lr), row = key = kt*16 + quad*4 + r.  kf shared across groups.
        f32x4 S[2][4];
        __builtin_amdgcn_s_setprio(1);
        #pragma unroll
        for (int kt = 0; kt < 4; ++kt) {
            bf16x8 kf0 = *(const bf16x8*)&Kb[(kt * 16 + lr) * 64 + s0];
            bf16x8 kf1 = *(const bf16x8*)&Kb[(kt * 16 + lr) * 64 + s1];
            S[0][kt] = __builtin_amdgcn_mfma_f32_16x16x32_bf16(kf0, qf[0][0], zero4, 0, 0, 0);
            S[1][kt] = __builtin_amdgcn_mfma_f32_16x16x32_bf16(kf0, qf[1][0], zero4, 0, 0, 0);
            S[0][kt] = __builtin_amdgcn_mfma_f32_16x16x32_bf16(kf1, qf[0][1], S[0][kt], 0, 0, 0);
            S[1][kt] = __builtin_amdgcn_mfma_f32_16x16x32_bf16(kf1, qf[1][1], S[1][kt], 0, 0, 0);
        }
        __builtin_amdgcn_s_setprio(0);

        // exp (unconditional, |S|<~3 so no overflow) -> single v_cndmask with SGPR lane-mask
        // -> in-register P^T redistribution into PV B-fragments.
        bf16x8 pf[2][2];
        #pragma unroll
        for (int g = 0; g < 2; ++g) {
            const unsigned long long* Mg = mq_w + g * 256 + kc * 16;
            float ev[16];
            #pragma unroll
            for (int kt = 0; kt < 4; ++kt)
                #pragma unroll
                for (int r = 0; r < 4; ++r)
                    ev[kt * 4 + r] = sel0(EXPD(S[g][kt][r]), Mg[kt * 4 + r]);
            // lane(quad,lr) holds P^T keys 16kt+4quad+{0..3}; B-frag needs keys 32ks+8quad+{0..7}.
            // (d0,d2) = permlane16_swap(permlane32_swap(pk(kt=2ks), pk(kt=2ks+1))), same for hi.
            #pragma unroll
            for (int ks = 0; ks < 2; ++ks) {
                const int ka = (2 * ks) * 4, kb2 = (2 * ks + 1) * 4;
                int d0 = cvtpk_bf16(ev[ka + 0], ev[ka + 1]);
                int d1 = cvtpk_bf16(ev[ka + 2], ev[ka + 3]);
                int d2 = cvtpk_bf16(ev[kb2 + 0], ev[kb2 + 1]);
                int d3 = cvtpk_bf16(ev[kb2 + 2], ev[kb2 + 3]);
                asm("v_permlane32_swap_b32 %0, %1" : "+v"(d0), "+v"(d2));
                asm("v_permlane16_swap_b32 %0, %1" : "+v"(d0), "+v"(d2));
                asm("v_permlane32_swap_b32 %0, %1" : "+v"(d1), "+v"(d3));
                asm("v_permlane16_swap_b32 %0, %1" : "+v"(d1), "+v"(d3));
                union { int di[4]; bf16x8 v; } pb;
                pb.di[0] = d0; pb.di[1] = d1; pb.di[2] = d2; pb.di[3] = d3;
                pf[g][ks] = pb.v;
            }
        }

        // O^T += V^T @ P^T ; V-frags shared across the two q-groups.  l via ones-MFMA.
        __builtin_amdgcn_s_setprio(1);
        #pragma unroll
        for (int ks = 0; ks < 2; ++ks) {
            const int sv = ks ? s1 : s0;
            Lacc[0] = __builtin_amdgcn_mfma_f32_16x16x32_bf16(onesf, pf[0][ks], Lacc[0], 0, 0, 0);
            Lacc[1] = __builtin_amdgcn_mfma_f32_16x16x32_bf16(onesf, pf[1][ks], Lacc[1], 0, 0, 0);
            #pragma unroll
            for (int mt = 0; mt < 4; ++mt) {
                bf16x8 vf = *(const bf16x8*)&Vb[(mt * 16 + lr) * 64 + sv];
                O[0][mt] = __builtin_amdgcn_mfma_f32_16x16x32_bf16(vf, pf[0][ks], O[0][mt], 0, 0, 0);
                O[1][mt] = __builtin_amdgcn_mfma_f32_16x16x32_bf16(vf, pf[1][ks], O[1][mt], 0, 0, 0);
            }
        }
        __builtin_amdgcn_s_setprio(0);
    }
    #pragma unroll
    for (int g = 0; g < 2; ++g) {
        // every row of the ones-MFMA result equals the column sum: l for q=lr is in Lacc[g][*].
        const float linv = 1.0f / Lacc[g][0];
        #pragma unroll
        for (int mt = 0; mt < 4; ++mt) {
            union { __bf16 b[4]; uint2 u; } pk;
            #pragma unroll
            for (int r = 0; r < 4; ++r) pk.b[r] = (__bf16)(O[g][mt][r] * linv);
            *(uint2*)&attn_out[((size_t)n * SEQ + qrow[g]) * EMB + h * 64 + mt * 16 + quad * 4] = pk.u;
        }
    }
}

// ---------------- Kernel 3a: Wo f32 -> bf16 ----------------
__global__ __launch_bounds__(256) void cvt_wo(const float* __restrict__ Wo, __bf16* __restrict__ Wob)
{
    int i = blockIdx.x * 256 + threadIdx.x;
    float4 f = *(const float4*)&Wo[(size_t)i * 4];
    union { __bf16 b[4]; uint2 u; } tmp;
    tmp.b[0] = (__bf16)f.x; tmp.b[1] = (__bf16)f.y; tmp.b[2] = (__bf16)f.z; tmp.b[3] = (__bf16)f.w;
    *(uint2*)&Wob[(size_t)i * 4] = tmp.u;
}

// ---------------- Kernel 3b: out = A(8192x1024) @ Wob^T + bo, MFMA ----------------
// v2: 64x128 tile, BK=64, global_load_lds staging (XOR-swizzled source, linear dest,
//     swizzled fragment reads), double-buffered LDS (48 KB), one barrier per K-step.
__global__ __launch_bounds__(256, 3) void out_gemm_mfma(
    const __bf16* __restrict__ A, const __bf16* __restrict__ B,
    const float* __restrict__ bo, float* __restrict__ out)
{
    __shared__ __align__(16) __bf16 AB[2][(64 + 128) * 64];   // [buf][A 4096 | B 8192]
    const int t = threadIdx.x, w = t >> 6, lane = t & 63, quad = lane >> 4, lr = lane & 15;
    const int wr = (w >> 1) * 32, wc = (w & 1) * 64;
    const int r0 = blockIdx.y * 64, e0 = blockIdx.x * 128;

    // staging: chunk c covers row c>>3, 16B-slot c&7 (swizzled on the source side)
    const int srow = t >> 3, sj = t & 7;
    const int sswz = (sj ^ (srow & 7)) * 8;            // (srow+32k)&7 == srow&7

    auto issue = [&](int st) {
        __bf16* buf = (__bf16*)&AB[st & 1][0];
        const __bf16* as = A + (size_t)(r0 + srow) * EMB + st * 64 + sswz;
        const __bf16* bs = B + (size_t)(e0 + srow) * EMB + st * 64 + sswz;
        gld16(as,            buf + t * 8);
        gld16(as + 32 * EMB, buf + t * 8 + 2048);
        gld16(bs,            buf + 4096 + t * 8);
        gld16(bs + 32 * EMB, buf + 4096 + t * 8 + 2048);
        gld16(bs + 64 * EMB, buf + 4096 + t * 8 + 4096);
        gld16(bs + 96 * EMB, buf + 4096 + t * 8 + 6144);
    };

    const int s0 = (quad ^ (lr & 7)) * 8, s1 = s0 ^ 32;
    const f32x4 zero4 = {0.f, 0.f, 0.f, 0.f};
    f32x4 acc[2][4];
    #pragma unroll
    for (int mt = 0; mt < 2; ++mt)
        #pragma unroll
        for (int nt = 0; nt < 4; ++nt) acc[mt][nt] = zero4;

    issue(0);
    for (int st = 0; st < 16; ++st) {
        __syncthreads();                   // vmcnt drained before barrier: tile st in LDS
        if (st + 1 < 16) issue(st + 1);
        const __bf16* buf = (const __bf16*)&AB[st & 1][0];
        #pragma unroll
        for (int ks = 0; ks < 2; ++ks) {
            const int sv = ks ? s1 : s0;
            bf16x8 af[2], bf[4];
            #pragma unroll
            for (int mt = 0; mt < 2; ++mt)
                af[mt] = *(const bf16x8*)&buf[(wr + mt * 16 + lr) * 64 + sv];
            #pragma unroll
            for (int nt = 0; nt < 4; ++nt)
                bf[nt] = *(const bf16x8*)&buf[4096 + (wc + nt * 16 + lr) * 64 + sv];
            __builtin_amdgcn_s_setprio(1);
            #pragma unroll
            for (int mt = 0; mt < 2; ++mt)
                #pragma unroll
                for (int nt = 0; nt < 4; ++nt)
                    acc[mt][nt] = __builtin_amdgcn_mfma_f32_16x16x32_bf16(af[mt], bf[nt], acc[mt][nt], 0, 0, 0);
            __builtin_amdgcn_s_setprio(0);
        }
    }
    float bv[4];
    #pragma unroll
    for (int nt = 0; nt < 4; ++nt) bv[nt] = bo[e0 + wc + nt * 16 + lr];
    #pragma unroll
    for (int mt = 0; mt < 2; ++mt)
        #pragma unroll
        for (int nt = 0; nt < 4; ++nt)
            #pragma unroll
            for (int rr = 0; rr < 4; ++rr)
                out[(size_t)(r0 + wr + mt * 16 + quad * 4 + rr) * EMB + e0 + wc + nt * 16 + lr] =
                    acc[mt][nt][rr] + bv[nt];
}

extern "C" void kernel_launch(void* const* d_in, const int* in_sizes, int n_in,
                              void* d_out, int out_size, void* d_ws, size_t ws_size,
                              hipStream_t stream) {
    const float* values = (const float*)d_in[0];
    const float* keys   = (const float*)d_in[1];
    const float* query  = (const float*)d_in[2];
    const int*   mask   = (const int*)d_in[3];
    const float* Wv     = (const float*)d_in[4];
    const float* Wk     = (const float*)d_in[5];
    const float* Wq     = (const float*)d_in[6];
    const float* Wo     = (const float*)d_in[7];
    const float* bo     = (const float*)d_in[8];
    float* out = (float*)d_out;

    const size_t per = (size_t)NB * HEADS * SEQ * HD;  // 8,388,608 elems
    __bf16* qp   = (__bf16*)d_ws;
    __bf16* kp   = qp + per;
    __bf16* vpt  = kp + per;                         // V transposed (N,H,64,SEQ)
    __bf16* attn = vpt + per;                        // (N*SEQ, EMB)
    __bf16* Wob  = attn + (size_t)NB * SEQ * EMB;
    unsigned long long* maskq = (unsigned long long*)(Wob + (size_t)EMB * EMB);  // 1 MB

    mask_perm<<<dim3(128, NB), 256, 0, stream>>>(mask, maskq);
    proj_mfma<<<dim3(16, 128, 3), 256, 0, stream>>>(query, keys, values, Wq, Wk, Wv, qp, kp, vpt);
    cvt_wo<<<1024, 256, 0, stream>>>(Wo, Wob);
    attn_mfma<<<1024, 256, 0, stream>>>(qp, kp, vpt, maskq, attn);
    out_gemm_mfma<<<dim3(EMB / 128, NB * SEQ / 64), 256, 0, stream>>>(attn, Wob, bo, out);
}